// Round 2
// baseline (219.107 us; speedup 1.0000x reference)
//
#include <hip/hip_runtime.h>
#include <hip/hip_bf16.h>

// DiagonalEmbedder: out[b,i] = 0.5 * ( x2@inv.T - 2 x@(mean*inv).T + c_i )
//   c_i = sum(mean^2*inv) + sum(log d) + sum(inv) - DIM
// Implemented as one bf16 MFMA GEMM with fp32-emulation via hi/lo split:
//   A' = [Ah | Ah | Al]  (4096 x 768),  B' = [Bh | Bl | Bh]  (8192 x 768)
//   dot(A',B') = Ah.Bh + Ah.Bl + Al.Bh  (~1e-5 rel error, fp32 accum)

#define BATCH 4096
#define N_IN  8192
#define DIM   128
#define KP    768           // 3 * 2*DIM
#define PD_THR 1e-6f

#define BM 128
#define BN 128
#define BK 64

typedef __attribute__((ext_vector_type(4))) float f32x4;
typedef __attribute__((ext_vector_type(8))) short bf16x8;

static __device__ __forceinline__ unsigned short f2bf(float v) {
    union { __hip_bfloat16 h; unsigned short u; } cv;
    cv.h = __float2bfloat16(v);
    return cv.u;
}
static __device__ __forceinline__ float bf2f(unsigned short u) {
    union { unsigned short u; __hip_bfloat16 h; } cv;
    cv.u = u;
    return __bfloat162float(cv.h);
}

// ---------------- prep A: features [x^2, x] split hi/lo ----------------
__global__ void prep_a_kernel(const float* __restrict__ x,
                              unsigned short* __restrict__ Ap) {
    int t = blockIdx.x * 256 + threadIdx.x;          // 0 .. BATCH*DIM
    int row = t >> 7;
    int d   = t & 127;
    float v  = x[t];
    float x2 = v * v;
    unsigned short x2h = f2bf(x2);
    unsigned short x2l = f2bf(x2 - bf2f(x2h));
    unsigned short xh  = f2bf(v);
    unsigned short xl  = f2bf(v - bf2f(xh));
    unsigned short* a = Ap + (size_t)row * KP;
    a[d]       = x2h;  a[128 + d] = xh;    // Ah
    a[256 + d] = x2h;  a[384 + d] = xh;    // Ah (dup, pairs with Bl)
    a[512 + d] = x2l;  a[640 + d] = xl;    // Al (pairs with Bh)
}

// ------- prep B: features [inv, -2*mean*inv] split hi/lo + c_i ---------
__global__ void prep_b_kernel(const float* __restrict__ mean,
                              const float* __restrict__ diag,
                              unsigned short* __restrict__ Bp,
                              float* __restrict__ cvec) {
    int wave = threadIdx.x >> 6, lane = threadIdx.x & 63;
    int row = blockIdx.x * 4 + wave;                 // one wave per row
    const float* mrow = mean + (size_t)row * DIM;
    const float* drow = diag + (size_t)row * DIM;
    unsigned short* b = Bp + (size_t)row * KP;
    float csum = 0.0f;
#pragma unroll
    for (int j = 0; j < 2; ++j) {
        int d = lane + 64 * j;
        float m   = mrow[d];
        float dd  = fmaxf(drow[d], PD_THR);
        float inv = 1.0f / dd;
        float fm  = -2.0f * m * inv;
        csum += m * m * inv + logf(dd) + inv;
        unsigned short ih = f2bf(inv);
        unsigned short il = f2bf(inv - bf2f(ih));
        unsigned short fh = f2bf(fm);
        unsigned short fl = f2bf(fm - bf2f(fh));
        b[d]       = ih;  b[128 + d] = fh;   // Bh
        b[256 + d] = il;  b[384 + d] = fl;   // Bl
        b[512 + d] = ih;  b[640 + d] = fh;   // Bh (dup)
    }
#pragma unroll
    for (int off = 32; off > 0; off >>= 1) csum += __shfl_down(csum, off);
    if (lane == 0) cvec[row] = csum - (float)DIM;
}

// ---------------- GEMM: C = A'(MxK) * B'(NxK)^T, m97 structure ----------------
// 128x128 tile, 4 waves (2x2), each wave 64x64 via 4x4 frags of 16x16x32 bf16.
__global__ void __launch_bounds__(256)
kl_gemm(const unsigned short* __restrict__ Ap,   // [BATCH][KP]
        const unsigned short* __restrict__ Bp,   // [N_IN][KP]
        const float* __restrict__ cvec,          // [N_IN]
        float* __restrict__ out) {               // [BATCH][N_IN]
    __shared__ unsigned short lds_a[BM * BK];    // 16 KB, linear [128][64]
    __shared__ unsigned short lds_b[BM * BK];    // 16 KB

    // Bijective XCD-aware swizzle (T1): nwg=2048, 8 XCDs, 2048%8==0.
    int bid0 = blockIdx.x;
    int bid  = (bid0 & 7) * ((BATCH / BM) * (N_IN / BN) / 8) + (bid0 >> 3);
    int bx = bid & 31;            // M tile index (32 tiles); consecutive swz ids
    int by = bid >> 5;            // share the same B panel -> L2 reuse
    int m0 = bx * BM;
    int n0 = by * BN;

    int tid  = threadIdx.x;
    int wave = tid >> 6, lane = tid & 63;
    int wr = wave >> 1, wc = wave & 1;

    f32x4 acc[4][4];
#pragma unroll
    for (int m = 0; m < 4; ++m)
#pragma unroll
        for (int n = 0; n < 4; ++n) acc[m][n] = (f32x4){0.f, 0.f, 0.f, 0.f};

    // staging: each wave stages 4 contiguous 1KB chunks per tile.
    // chunk c covers rows c*8..c*8+7 (row = 128B). lane l -> byte base + l*16.
    const int srow = wave * 32 + (lane >> 3);   // + j*8
    const int scol = (lane & 7) * 8;            // element col within BK

    for (int k0 = 0; k0 < KP; k0 += BK) {
#pragma unroll
        for (int j = 0; j < 4; ++j) {
            int r = srow + j * 8;
            const unsigned short* ga = Ap + (size_t)(m0 + r) * KP + k0 + scol;
            const unsigned short* gb = Bp + (size_t)(n0 + r) * KP + k0 + scol;
            unsigned short* la = lds_a + (wave * 4 + j) * 512;   // bytes: *1024
            unsigned short* lb = lds_b + (wave * 4 + j) * 512;
            __builtin_amdgcn_global_load_lds(
                (const __attribute__((address_space(1))) void*)ga,
                (__attribute__((address_space(3))) void*)la, 16, 0, 0);
            __builtin_amdgcn_global_load_lds(
                (const __attribute__((address_space(1))) void*)gb,
                (__attribute__((address_space(3))) void*)lb, 16, 0, 0);
        }
        __syncthreads();   // drains vmcnt(0): staged data visible

#pragma unroll
        for (int kk = 0; kk < BK; kk += 32) {
            bf16x8 af[4], bfr[4];
#pragma unroll
            for (int m = 0; m < 4; ++m)
                af[m] = *(const bf16x8*)&lds_a[(wr * 64 + m * 16 + (lane & 15)) * BK
                                               + kk + (lane >> 4) * 8];
#pragma unroll
            for (int n = 0; n < 4; ++n)
                bfr[n] = *(const bf16x8*)&lds_b[(wc * 64 + n * 16 + (lane & 15)) * BK
                                                + kk + (lane >> 4) * 8];
#pragma unroll
            for (int m = 0; m < 4; ++m)
#pragma unroll
                for (int n = 0; n < 4; ++n)
                    acc[m][n] = __builtin_amdgcn_mfma_f32_16x16x32_bf16(
                        af[m], bfr[n], acc[m][n], 0, 0, 0);
        }
        __syncthreads();   // protect LDS before next stage
    }

    // epilogue: C/D layout col=lane&15, row=(lane>>4)*4+reg (m89-verified)
    int crow = m0 + wr * 64 + ((lane >> 4) << 2);
    int ccol = n0 + wc * 64 + (lane & 15);
#pragma unroll
    for (int n = 0; n < 4; ++n) {
        int col = ccol + n * 16;
        float cc = cvec[col];
#pragma unroll
        for (int m = 0; m < 4; ++m) {
            int rbase = crow + m * 16;
#pragma unroll
            for (int r = 0; r < 4; ++r)
                out[(size_t)(rbase + r) * N_IN + col] = 0.5f * (acc[m][n][r] + cc);
        }
    }
}

extern "C" void kernel_launch(void* const* d_in, const int* in_sizes, int n_in_args,
                              void* d_out, int out_size, void* d_ws, size_t ws_size,
                              hipStream_t stream) {
    (void)in_sizes; (void)n_in_args; (void)out_size; (void)ws_size;
    const float* x    = (const float*)d_in[0];
    const float* mean = (const float*)d_in[1];
    const float* diag = (const float*)d_in[2];
    float* out = (float*)d_out;

    char* ws = (char*)d_ws;
    unsigned short* Bp = (unsigned short*)ws;                              // 12.0 MB
    unsigned short* Ap = (unsigned short*)(ws + (size_t)N_IN * KP * 2);    //  6.0 MB
    float* cvec = (float*)(ws + (size_t)N_IN * KP * 2 + (size_t)BATCH * KP * 2); // 32 KB

    prep_a_kernel<<<BATCH * DIM / 256, 256, 0, stream>>>(x, Ap);
    prep_b_kernel<<<N_IN / 4, 256, 0, stream>>>(mean, diag, Bp, cvec);
    kl_gemm<<<(BATCH / BM) * (N_IN / BN), 256, 0, stream>>>(Ap, Bp, cvec, out);
}